// Round 18
// baseline (131.932 us; speedup 1.0000x reference)
//
#include <hip/hip_runtime.h>
#include <hip/hip_bf16.h>

typedef _Float16 f16x8 __attribute__((ext_vector_type(8)));
typedef float f32x4 __attribute__((ext_vector_type(4)));

#define TAU_Q 164           // ceil(5e-3 * 32768) = 10 sigma of 1-term fp16 dot noise (sigma~5e-4)
#define MASK_Q 2098790u     // (64.05)*32768: best-below -> rescue (masked-proto / all-negative guard)

typedef const __attribute__((address_space(1))) void gas_void;
typedef __attribute__((address_space(3))) void las_void;

__device__ __forceinline__ void gload_lds16(const void* g, void* l) {
  // async global->LDS DMA, 16B/lane; LDS dest = wave-uniform base + lane*16
  __builtin_amdgcn_global_load_lds((gas_void*)g, (las_void*)l, 16, 0, 0);
}

// ---------------- kernel 1: per-proto norm + fp16-hi pack ----------------
// q[m] = counts>0 ? 1/||p_m|| : 0. B-hat = fp16(P*q), packed so MFMA B-fragment
// (p16=m>>4, kc) at lane L sits at byte (p16*8+kc)*1024 + L*16 (coalesced 1KB chunks).
// Masked protos: qm=0 -> all-zero fragments -> dot contributes exactly 0 (caught by MASK_Q).
__global__ __launch_bounds__(64) void prep_kernel(
    const float* __restrict__ P, const int* __restrict__ counts,
    float* __restrict__ q, int* __restrict__ wcount, f16x8* __restrict__ bhi) {
  const int m = blockIdx.x, lane = threadIdx.x;
  if (m == 0 && lane == 0) *wcount = 0;
  float4 v = *reinterpret_cast<const float4*>(P + (size_t)m * 256 + lane * 4);
  float s = v.x * v.x + v.y * v.y + v.z * v.z + v.w * v.w;
  for (int off = 32; off > 0; off >>= 1) s += __shfl_xor(s, off, 64);
  const float qm = (counts[m] > 0) ? (1.0f / sqrtf(s)) : 0.0f;
  if (lane == 0) q[m] = qm;
  if (lane < 32) {
    const int kg = lane;  // 8 k-elements per lane
    const float* src = P + (size_t)m * 256 + kg * 8;
    float4 v0 = *reinterpret_cast<const float4*>(src);
    float4 v1 = *reinterpret_cast<const float4*>(src + 4);
    float pe[8] = {v0.x, v0.y, v0.z, v0.w, v1.x, v1.y, v1.z, v1.w};
    f16x8 hi;
#pragma unroll
    for (int t = 0; t < 8; ++t) hi[t] = (_Float16)(pe[t] * qm);
    const int dst = ((m >> 4) * 8 + (kg >> 2)) * 64 + (kg & 3) * 16 + (m & 15);
    bhi[dst] = hi;
  }
}

// ---------------- kernel 2: fp16 MFMA screen, BM=256 with SHARED (non-redundant) B staging ---
// 512 threads = 8 waves (4 rg of 64 rows x 2 cg of 64 protos). Wave tile 64x64: 16 MFMA/step.
// A: E hi fp16, 256 rows x K=256 = 128KB LDS, XOR-swizzled.
// B: 8KB/step (8 x 1KB chunks; EACH WAVE DMAs EXACTLY ONE chunk), double-buffered 2x8KB,
// per-step __syncthreads = the DMA fence (r12-proven; r13 lesson: the barrier's vmcnt drain
// is what orders global_load_lds vs ds_read).
// WHY: r12/r14/r16/r17 all landed 68-80us regardless of sync structure/occupancy; the shared
// invariant was ~1-2MB of B per CU through the VMEM->LDS DMA return path (wave-private
// staging = 4x redundant). BM=256 + shared staging cuts that to 512KB/CU (B staged ONCE).
// Steps: 8 pt x 8 kc = 64. VGPR ~105 < the 512-thread 128 cap (no persistent B regs).
__global__ __launch_bounds__(512) void screen_kernel(
    const float* __restrict__ E, const f16x8* __restrict__ bhi,
    int* __restrict__ out, int* __restrict__ wcount,
    int* __restrict__ wl, int wlcap) {
  __shared__ __align__(16) unsigned char ldsA[131072];  // 256 rows x 512B (hi fp16, K=256)
  __shared__ __align__(16) unsigned char ldsB[16384];   // 2 bufs x 8KB (8 chunks of 1KB)

  const int tid = threadIdx.x;
  const int wave = tid >> 6, lane = tid & 63;
  const int rg = wave >> 1, cg = wave & 1;
  const int g = lane >> 4, c = lane & 15;
  const int blockRow = blockIdx.x * 256;
  const char* bhiB = (const char*)bhi;

  // ---- B stage: DMA step t=(pt,kc) into buffer b; this wave stages chunk `wave` ----
  // chunk w holds p16 = pt*8 + w  (read side: wave (rg,cg) consumes chunks cg*4+fc)
  auto stageB = [&](int b, int t) {
    const int ptn = t >> 3, kcn = t & 7;
    const size_t src = (size_t)((((ptn * 8 + wave) * 8 + kcn) << 10)) + (size_t)lane * 16;
    gload_lds16(bhiB + src, (char*)ldsB + b * 8192 + wave * 1024);
  };

  stageB(0, 0);

  // ---- stage A once: E[blockRow..+256][0..256) f32 -> hi fp16, swizzled ----
  {
    const int row = tid >> 1, half = tid & 1;  // 2 threads/row, 128 k each
    const float* src = E + (size_t)(blockRow + row) * 256 + half * 128;
    const int rswz = (row & 7) << 4;
#pragma unroll
    for (int o = 0; o < 16; ++o) {
      float4 v0 = *reinterpret_cast<const float4*>(src + o * 8);
      float4 v1 = *reinterpret_cast<const float4*>(src + o * 8 + 4);
      float e[8] = {v0.x, v0.y, v0.z, v0.w, v1.x, v1.y, v1.z, v1.w};
      f16x8 hi;
#pragma unroll
      for (int t = 0; t < 8; ++t) hi[t] = (_Float16)e[t];
      const int byte = (row * 512 + (half * 128 + o * 8) * 2) ^ rswz;
      *reinterpret_cast<f16x8*>(ldsA + byte) = hi;
    }
  }
  __syncthreads();  // A staged + first B landed (barrier drains the DMA)

  // quantized top-2 per lane: 16 row-slots (row = rg*64 + (s>>2)*16 + g*4 + (s&3))
  unsigned t1[16], t2[16];
#pragma unroll
  for (int s = 0; s < 16; ++s) { t1[s] = 0u; t2[s] = 0u; }

  int buf = 0;
#pragma unroll 1
  for (int pt = 0; pt < 8; ++pt) {
    f32x4 acc[4][4];
#pragma unroll
    for (int fr = 0; fr < 4; ++fr)
#pragma unroll
      for (int fc = 0; fc < 4; ++fc) acc[fr][fc] = (f32x4){0.f, 0.f, 0.f, 0.f};

#pragma unroll
    for (int kc = 0; kc < 8; ++kc) {
      const int t = pt * 8 + kc;
      if (t < 63) stageB(buf ^ 1, t + 1);  // issue early: covered by reads+MFMA below

      // ---- A fragments (4) ----
      f16x8 ah[4];
#pragma unroll
      for (int fr = 0; fr < 4; ++fr) {
        const int rowA = rg * 64 + fr * 16 + c;
        const int ab = (rowA * 512 + kc * 64 + g * 16) ^ ((rowA & 7) << 4);
        ah[fr] = *reinterpret_cast<const f16x8*>(ldsA + ab);
      }
      // ---- B fragments (4, contiguous 1KB chunks) + 16 MFMA ----
      const char* bbase = (const char*)ldsB + buf * 8192 + (cg * 4) * 1024 + (size_t)lane * 16;
      f16x8 bf[4];
#pragma unroll
      for (int fc = 0; fc < 4; ++fc) bf[fc] = *reinterpret_cast<const f16x8*>(bbase + fc * 1024);
#pragma unroll
      for (int fr = 0; fr < 4; ++fr)
#pragma unroll
        for (int fc = 0; fc < 4; ++fc)
          acc[fr][fc] = __builtin_amdgcn_mfma_f32_16x16x32_f16(ah[fr], bf[fc], acc[fr][fc], 0, 0, 0);

      __syncthreads();  // drains the DMA (vmcnt) + all waves done reading buf
      buf ^= 1;
    }

    // ---- fold this pt's 64 proto-columns (per cg) into quantized top-2 ----
#pragma unroll
    for (int fc = 0; fc < 4; ++fc) {
      const unsigned mp = (unsigned)(1023 - (pt * 128 + cg * 64 + fc * 16 + c));
#pragma unroll
      for (int fr = 0; fr < 4; ++fr)
#pragma unroll
        for (int reg = 0; reg < 4; ++reg) {
          const int s = fr * 4 + reg;
          const float v = acc[fr][fc][reg];
          const unsigned k = ((unsigned)fmaf(v, 32768.0f, 2097152.0f) << 10) | mp;
          const unsigned lo = (k < t1[s]) ? k : t1[s];
          t1[s] = (k > t1[s]) ? k : t1[s];
          t2[s] = (lo > t2[s]) ? lo : t2[s];
        }
    }
  }

  // ---- cross-lane top-2 merge over the 16 c-lanes sharing each row ----
#pragma unroll
  for (int s = 0; s < 16; ++s) {
#pragma unroll
    for (int off = 1; off <= 8; off <<= 1) {
      const unsigned o1 = (unsigned)__shfl_xor((int)t1[s], off);
      const unsigned o2 = (unsigned)__shfl_xor((int)t2[s], off);
      const unsigned lo = (o1 < t1[s]) ? o1 : t1[s];
      t1[s] = (o1 > t1[s]) ? o1 : t1[s];
      const unsigned hi2 = (o2 > t2[s]) ? o2 : t2[s];
      t2[s] = (lo > hi2) ? lo : hi2;
    }
  }

  __syncthreads();  // all LDS use done -> reuse ldsA for cross-cg merge
  unsigned* mg = reinterpret_cast<unsigned*>(ldsA);  // [256 rows][2 cg][2]
  if (c == 0) {
#pragma unroll
    for (int s = 0; s < 16; ++s) {
      const int row = rg * 64 + (s >> 2) * 16 + g * 4 + (s & 3);
      mg[(row * 2 + cg) * 2 + 0] = t1[s];
      mg[(row * 2 + cg) * 2 + 1] = t2[s];
    }
  }
  __syncthreads();
  if (tid < 256) {
    const unsigned a1v = mg[(tid * 2 + 0) * 2 + 0], a2v = mg[(tid * 2 + 0) * 2 + 1];
    const unsigned b1v = mg[(tid * 2 + 1) * 2 + 0], b2v = mg[(tid * 2 + 1) * 2 + 1];
    const unsigned lo = (a1v < b1v) ? a1v : b1v;
    const unsigned T1 = (a1v > b1v) ? a1v : b1v;
    unsigned T2 = (a2v > b2v) ? a2v : b2v;
    T2 = (lo > T2) ? lo : T2;
    const int grow = blockRow + tid;
    out[grow] = 1023 - (int)(T1 & 1023u);
    const unsigned iq1 = T1 >> 10, iq2 = T2 >> 10;
    if ((int)(iq1 - iq2) < TAU_Q || iq1 < MASK_Q) {
      const int p = atomicAdd(wcount, 1);
      if (p < wlcap) wl[p] = grow;
    }
  }
}

// ---------------- kernel 3: exact f32 rescue over the worklist (16 rows/batch) ----------------
// Round-1-identical accumulation per (row, proto): ONE ascending-k fmaf chain over k=0..255
// (x,y,z,w within each float4), then v = acc*q, ties to the smaller proto index.
__global__ __launch_bounds__(256) void rescue_kernel(
    const float* __restrict__ E, const float* __restrict__ P,
    const float* __restrict__ q, int* __restrict__ out,
    const int* __restrict__ wcount, const int* __restrict__ wl, int wlcap) {
  __shared__ float Elds[16][260];
  __shared__ int rowsS[16];
  __shared__ float wv[16][4];
  __shared__ int wm[16][4];

  const int tid = threadIdx.x;
  const int wave = tid >> 6, lane = tid & 63;
  int total = *wcount;
  if (total > wlcap) total = wlcap;

  for (int b0 = blockIdx.x * 16; b0 < total; b0 += gridDim.x * 16) {
    const int nb = min(16, total - b0);
    __syncthreads();
    if (tid < 16) rowsS[tid] = wl[b0 + (tid < nb ? tid : 0)];
    __syncthreads();
#pragma unroll
    for (int u = 0; u < 4; ++u) {
      const int unit = u * 256 + tid, r = unit >> 6, k4 = unit & 63;
      *reinterpret_cast<float4*>(&Elds[r][k4 * 4]) =
          *reinterpret_cast<const float4*>(E + (size_t)rowsS[r] * 256 + k4 * 4);
    }
    __syncthreads();

    float acc[16][4];  // 16 rows x 4 protos (m = tid + 256*j)
#pragma unroll
    for (int r = 0; r < 16; ++r)
#pragma unroll
      for (int j = 0; j < 4; ++j) acc[r][j] = 0.f;

    for (int k16 = 0; k16 < 16; ++k16) {  // 16 consecutive k per step
#pragma unroll
      for (int jp = 0; jp < 2; ++jp) {    // protos in pairs (register budget)
        float4 pv[2][4];
#pragma unroll
        for (int jj = 0; jj < 2; ++jj) {
          const float* ps = P + (size_t)(tid + 256 * (jp * 2 + jj)) * 256 + k16 * 16;
#pragma unroll
          for (int u = 0; u < 4; ++u)
            pv[jj][u] = *reinterpret_cast<const float4*>(ps + u * 4);
        }
#pragma unroll
        for (int r = 0; r < 16; ++r) {
#pragma unroll
          for (int jj = 0; jj < 2; ++jj) {
            const int j = jp * 2 + jj;
            float a = acc[r][j];
#pragma unroll
            for (int u = 0; u < 4; ++u) {
              const float4 ev = *reinterpret_cast<const float4*>(&Elds[r][k16 * 16 + u * 4]);
              a = fmaf(pv[jj][u].x, ev.x, a);
              a = fmaf(pv[jj][u].y, ev.y, a);
              a = fmaf(pv[jj][u].z, ev.z, a);
              a = fmaf(pv[jj][u].w, ev.w, a);
            }
            acc[r][j] = a;
          }
        }
      }
    }

    float qv[4];
#pragma unroll
    for (int j = 0; j < 4; ++j) qv[j] = q[tid + 256 * j];

#pragma unroll
    for (int r = 0; r < 16; ++r) {
      float bv = -3.0e38f;
      int bm = 0;
#pragma unroll
      for (int j = 0; j < 4; ++j) {  // m ascending -> strict > keeps lowest m
        const float v = (qv[j] > 0.f) ? acc[r][j] * qv[j] : -1.0e30f;
        if (v > bv) { bv = v; bm = tid + 256 * j; }
      }
#pragma unroll
      for (int off = 1; off <= 32; off <<= 1) {
        const float ov = __shfl_xor(bv, off);
        const int om = __shfl_xor(bm, off);
        if (ov > bv || (ov == bv && om < bm)) { bv = ov; bm = om; }
      }
      if (lane == 0) { wv[r][wave] = bv; wm[r][wave] = bm; }
    }
    __syncthreads();
    if (tid < 16) {
      float bv = wv[tid][0];
      int bm = wm[tid][0];
#pragma unroll
      for (int w = 1; w < 4; ++w) {
        const float ov = wv[tid][w];
        const int om = wm[tid][w];
        if (ov > bv || (ov == bv && om < bm)) { bv = ov; bm = om; }
      }
      if (tid < nb) out[rowsS[tid]] = bm;
    }
    __syncthreads();
  }
}

extern "C" void kernel_launch(void* const* d_in, const int* in_sizes, int n_in,
                              void* d_out, int out_size, void* d_ws, size_t ws_size,
                              hipStream_t stream) {
  const float* E = (const float*)d_in[0];
  const float* P = (const float*)d_in[1];
  const int* counts = (const int*)d_in[2];
  const int M = in_sizes[2];            // 1024
  const int Dd = in_sizes[1] / M;       // 256
  const int N = in_sizes[0] / Dd;       // 65536
  int* out = (int*)d_out;

  // workspace: q (4KB) | wcount @4096 | bhi @8192 (512KB) | worklist @532480
  float* qv = (float*)d_ws;
  int* wcount = (int*)((char*)d_ws + 4096);
  f16x8* bhi = (f16x8*)((char*)d_ws + 8192);
  int* wl = (int*)((char*)d_ws + 8192 + 524288);
  long long cap = ((long long)ws_size - (8192 + 524288)) / 4;
  if (cap < 0) cap = 0;
  if (cap > N) cap = N;
  int wlcap = (int)cap;

  prep_kernel<<<M, 64, 0, stream>>>(P, counts, qv, wcount, bhi);
  screen_kernel<<<N / 256, 512, 0, stream>>>(E, bhi, out, wcount, wl, wlcap);
  rescue_kernel<<<256, 256, 0, stream>>>(E, P, qv, out, wcount, wl, wlcap);
}